// Round 6
// baseline (310.088 us; speedup 1.0000x reference)
//
#include <hip/hip_runtime.h>
#include <math.h>

// B=4, S=2048, HID=1024, H=8, KV=2, HD=128, G=4, M=8192
#define SCALE_ 0.08838834764831845f  // 1/sqrt(128)
#define PSHIFT 8.0f   // softmax exponent shift (see prior rounds)
#define LOG2E_ 1.4426950408889634f
#define PSH2_  11.541560327111707f   // PSHIFT * log2(e)

typedef __attribute__((ext_vector_type(8))) short short8;     // 8 bf16 = 4 VGPR
typedef __attribute__((ext_vector_type(4))) float floatx4;
typedef __attribute__((ext_vector_type(4))) _Float16 half4;   // 4 f16 = 2 VGPR
typedef __attribute__((ext_vector_type(8))) _Float16 half8;   // 8 f16 = 4 VGPR

__device__ inline short f2bf(float x) {
    union { float f; unsigned u; } v; v.f = x;
    unsigned r = v.u + 0x7fff + ((v.u >> 16) & 1);   // RNE
    return (short)(r >> 16);
}
__device__ inline float bf2f(short h) {
    union { float f; unsigned u; } v; v.u = ((unsigned)(unsigned short)h) << 16;
    return v.f;
}

// ---------------------------------------------------------------------------
// Prep (fused): blocks [0,8192) = X fp32->bf16 + bias concat;
//               blocks [8192,11776) = weight transpose+convert.
// ---------------------------------------------------------------------------
__global__ __launch_bounds__(256) void prep_fused(
    const float* __restrict__ X, short* __restrict__ Xb,
    const float* __restrict__ bq, const float* __restrict__ bk2,
    const float* __restrict__ bv2, float* __restrict__ bcat,
    const float* __restrict__ Wq, const float* __restrict__ Wk,
    const float* __restrict__ Wv, const float* __restrict__ Wo,
    short* __restrict__ Wt, short* __restrict__ Wot)
{
    __shared__ float T[32][33];
    const int bid = blockIdx.x;
    const int t = threadIdx.x;
    if (bid < 8192) {
        const int gid = bid * 256 + t;
        if (gid < 2097152) {
            const float4 v = ((const float4*)X)[gid];
            short4 o;
            o.x = f2bf(v.x); o.y = f2bf(v.y); o.z = f2bf(v.z); o.w = f2bf(v.w);
            ((short4*)Xb)[gid] = o;
        }
        if (gid < 2560)
            bcat[gid] = (gid < 2048) ? bq[gid]
                      : (gid < 2304) ? bk2[gid - 2048] : bv2[gid - 2304];
        return;
    }
    const int t2 = bid - 8192;
    const int k0 = (t2 & 31) * 32;
    const int ny = t2 >> 5;
    const float* src; int ldn, ncol0, nrow0; short* dst;
    if (ny < 80) {
        const int n0 = ny * 32;
        if (n0 < 2048)      { src = Wq; ldn = 2048; ncol0 = n0; }
        else if (n0 < 2304) { src = Wk; ldn = 256;  ncol0 = n0 - 2048; }
        else                { src = Wv; ldn = 256;  ncol0 = n0 - 2304; }
        dst = Wt; nrow0 = n0;
    } else {
        const int n0 = (ny - 80) * 32;
        src = Wo; ldn = 1024; ncol0 = n0; dst = Wot; nrow0 = n0;
    }
    {
        const int r = t >> 3, c4 = (t & 7) * 4;
        const float4 v = *(const float4*)&src[(size_t)(k0 + r) * ldn + ncol0 + c4];
        T[r][c4 + 0] = v.x; T[r][c4 + 1] = v.y; T[r][c4 + 2] = v.z; T[r][c4 + 3] = v.w;
    }
    __syncthreads();
    {
        const int nr = t >> 3, kc4 = (t & 7) * 4;
        short4 o;
        o.x = f2bf(T[kc4 + 0][nr]);
        o.y = f2bf(T[kc4 + 1][nr]);
        o.z = f2bf(T[kc4 + 2][nr]);
        o.w = f2bf(T[kc4 + 3][nr]);
        *(short4*)&dst[(size_t)(nrow0 + nr) * 1024 + k0 + kc4] = o;
    }
}

// ---------------------------------------------------------------------------
// Pass 1: QKV+gate projection, bf16 MFMA (m97 structure) + XCD row-panel
// swizzle (XCD x owns row-blocks [x*8, x*8+8), sweeping all 20 col-blocks:
// A-panel L2-resident, B streams in column order).
// ---------------------------------------------------------------------------
__global__ __launch_bounds__(256) void qkv_mfma(
    const short* __restrict__ Ag, const short* __restrict__ Bg,
    const float* __restrict__ bcat,
    short* __restrict__ qb, short* __restrict__ kb,
    short* __restrict__ vb, short* __restrict__ gateb)
{
    __shared__ short As[128 * 64];
    __shared__ short Bs[128 * 64];
    const int tid = threadIdx.x;
    const int wave = tid >> 6, lane = tid & 63;
    const int quad = lane >> 4, l16 = lane & 15;
    const int wm = wave & 1, wn = wave >> 1;
    const int lin = blockIdx.x;
    const int xcd = lin & 7;
    const int idx = lin >> 3;                  // 0..159
    const int rr_ = idx / 20;                  // 0..7
    const int m0 = (xcd * 8 + rr_) * 128;
    const int n0 = (idx - rr_ * 20) * 128;

    floatx4 acc[4][4] = {};

    for (int k0 = 0; k0 < 1024; k0 += 64) {
        __syncthreads();
        #pragma unroll
        for (int c = 0; c < 4; ++c) {
            const int blk = (c * 4 + wave) * 64 + lane;   // 16B-block 0..1023
            const int row = blk >> 3, p = blk & 7;
            const int col = (p ^ (row & 7)) << 3;
            __builtin_amdgcn_global_load_lds(
                (const __attribute__((address_space(1))) unsigned int*)(Ag + (size_t)(m0 + row) * 1024 + k0 + col),
                (__attribute__((address_space(3))) unsigned int*)&As[(c * 4 + wave) * 512],
                16, 0, 0);
            __builtin_amdgcn_global_load_lds(
                (const __attribute__((address_space(1))) unsigned int*)(Bg + (size_t)(n0 + row) * 1024 + k0 + col),
                (__attribute__((address_space(3))) unsigned int*)&Bs[(c * 4 + wave) * 512],
                16, 0, 0);
        }
        __syncthreads();
        #pragma unroll
        for (int ks = 0; ks < 2; ++ks) {
            short8 af[4], bfr[4];
            #pragma unroll
            for (int mt = 0; mt < 4; ++mt) {
                const int row = wm * 64 + mt * 16 + l16;
                const int p = (ks * 4 + quad) ^ (row & 7);
                af[mt] = *(const short8*)&As[row * 64 + p * 8];
            }
            #pragma unroll
            for (int nt = 0; nt < 4; ++nt) {
                const int row = wn * 64 + nt * 16 + l16;
                const int p = (ks * 4 + quad) ^ (row & 7);
                bfr[nt] = *(const short8*)&Bs[row * 64 + p * 8];
            }
            #pragma unroll
            for (int mt = 0; mt < 4; ++mt)
                #pragma unroll
                for (int nt = 0; nt < 4; ++nt)
                    acc[mt][nt] = __builtin_amdgcn_mfma_f32_16x16x32_bf16(af[mt], bfr[nt], acc[mt][nt], 0, 0, 0);
        }
    }

    #pragma unroll
    for (int nt = 0; nt < 4; ++nt) {
        const int n = n0 + wn * 64 + nt * 16 + l16;
        const float bias = bcat[n];
        #pragma unroll
        for (int mt = 0; mt < 4; ++mt) {
            #pragma unroll
            for (int r = 0; r < 4; ++r) {
                const int m = m0 + wm * 64 + mt * 16 + quad * 4 + r;
                const int b = m >> 11, s = m & 2047;
                const short o = f2bf(acc[mt][nt][r] + bias);
                if (n < 2048) {
                    const int kv = n >> 10, rr = n & 1023;
                    if (rr < 512) {
                        const int h = kv * 4 + (rr >> 7), d = rr & 127;
                        qb[(((size_t)(b * 8 + h)) * 2048 + s) * 128 + d] = o;
                    } else {
                        const int r2 = rr - 512;
                        const int h = kv * 4 + (r2 >> 7), d = r2 & 127;
                        gateb[(size_t)m * 1024 + h * 128 + d] = o;
                    }
                } else if (n < 2304) {
                    const int c = n - 2048;
                    kb[(((size_t)(b * 2 + (c >> 7))) * 2048 + s) * 128 + (c & 127)] = o;
                } else {
                    const int c = n - 2304;
                    vb[(((size_t)(b * 2 + (c >> 7))) * 2048 + s) * 128 + (c & 127)] = o;
                }
            }
        }
    }
}

// ---------------------------------------------------------------------------
// Pass 2 (fused): blocks [0,20480) = RMSNorm+RoPE on q/k;
//                 blocks [20480,22528) = V transpose with k-permutation.
// ---------------------------------------------------------------------------
__global__ __launch_bounds__(256) void norm_vtrans(
    short* __restrict__ qb, short* __restrict__ kb,
    const float* __restrict__ rope,
    const float* __restrict__ qw, const float* __restrict__ kw,
    const short* __restrict__ vb, _Float16* __restrict__ vt)
{
    __shared__ float T[32][33];
    const int bid = blockIdx.x;
    const int t = threadIdx.x;
    if (bid < 20480) {
        const int row = bid * 4 + (t >> 6);
        short* base; const float* w; int s; float scl;
        if (row < 65536) { base = qb + (size_t)row * 128; s = row & 2047; w = qw; scl = SCALE_; }
        else { const int r2 = row - 65536; base = kb + (size_t)r2 * 128; s = r2 & 2047; w = kw; scl = 1.0f; }
        const int lane = t & 63;
        const short2 xv = *(const short2*)&base[lane * 2];
        const float x0 = bf2f(xv.x), x1 = bf2f(xv.y);
        float ssq = x0 * x0 + x1 * x1;
        #pragma unroll
        for (int off = 1; off < 64; off <<= 1) ssq += __shfl_xor(ssq, off);
        const float inv = rsqrtf(ssq * (1.0f / 128.0f) + 1e-6f);
        const float a = x0 * inv * w[lane * 2];
        const float b = x1 * inv * w[lane * 2 + 1];
        const float* er = rope + (size_t)s * 256;
        const float sin0 = er[lane * 2], sin1 = er[lane * 2 + 1];
        const float cos0 = er[128 + lane * 2], cos1 = er[128 + lane * 2 + 1];
        short2 o;
        o.x = f2bf((a * cos0 - b * sin0) * scl);
        o.y = f2bf((b * cos1 + a * sin1) * scl);
        *(short2*)&base[lane * 2] = o;
        return;
    }
    // ---- V transpose: bf16 (B,KV,S,HD) -> VT (B,KV,HD,S) f16, s-permuted
    // within each 32-block (4q+r -> 8q+r ; 16+4q+r -> 8q+4+r) to match the
    // K=32 f16 MFMA B-frag slots of the QK^T C-layout.
    const int t2 = bid - 20480;
    const int s0 = (t2 & 63) * 32, d0 = ((t2 >> 6) & 3) * 32, bk = t2 >> 8;
    const short* src = vb + ((size_t)bk * 2048 + s0) * 128 + d0;
    {
        const int sr = t >> 3, c4 = (t & 7) * 4;
        const short4 xv = *(const short4*)&src[sr * 128 + c4];
        T[sr][c4 + 0] = bf2f(xv.x);
        T[sr][c4 + 1] = bf2f(xv.y);
        T[sr][c4 + 2] = bf2f(xv.z);
        T[sr][c4 + 3] = bf2f(xv.w);
    }
    __syncthreads();
    {
        const int dr = t >> 3, sc4 = (t & 7) * 4;
        const int cs = sc4 >> 2;                                   // chunk 0..7
        const int nc = (cs < 4) ? (cs << 1) : (((cs - 4) << 1) | 1); // permuted
        half4 o;
        o[0] = (_Float16)T[sc4 + 0][dr];
        o[1] = (_Float16)T[sc4 + 1][dr];
        o[2] = (_Float16)T[sc4 + 2][dr];
        o[3] = (_Float16)T[sc4 + 3][dr];
        *(half4*)&vt[((size_t)bk * 128 + d0 + dr) * 2048 + s0 + nc * 4] = o;
    }
}

// ---------------------------------------------------------------------------
// Pass 3: MFMA flash attention + fused sigmoid gating. Round-14:
// CONTROLLED REVERT of the attn XCD swizzle. Evidence ledger:
//   r1 (no swizzle):            87.8 us, FETCH 49 MB, Occ 26
//   r2 (swizzle+setprio):       98.6 us, FETCH 21 MB
//   r4 (swizzle only):          97.4 us  -> setprio was NOT the regression
//   r5 (swizzle+stagger):       97.5 us  -> lockstep-L2-contention refuted
// => the swizzle itself costs ~10 us DESPITE halving HBM fetch and making
// K/V L2-resident: L2-locality is the wrong lever for this latency-bound
// kernel. Natural round-robin mapping (2D grid, bh=blockIdx.y) restored.
// Kept: exp2+fma softmax (absmax identical r1 vs r2-r5).
// Structure: 256 thr, 4 waves x 32 q rows, QBLK=128, dbuf gload_lds,
// one barrier per kt, launch_bounds(256,2).
// ---------------------------------------------------------------------------
__global__ __launch_bounds__(256, 2) void attn_mfma(
    const short* __restrict__ qb, const short* __restrict__ kb,
    const _Float16* __restrict__ vt, const short* __restrict__ gateb,
    short* __restrict__ xo)
{
    __shared__ short    Ks[2][64 * 128];    // 16 KB per buffer
    __shared__ _Float16 VTs[2][128 * 64];   // 16 KB per buffer

    const int tid = threadIdx.x;
    const int wave = tid >> 6, lane = tid & 63;
    const int quad = lane >> 4, l16 = lane & 15;
    const int bh = blockIdx.y, b = bh >> 3, h = bh & 7, kv = h >> 2;
    const int q0 = blockIdx.x * 128;

    // Q B-frags: qf[ks][u]: B[k=quad*8+j][n=l16] = Q[q0+wave*32+u*16+l16][ks*32+quad*8+j]
    short8 qf[4][2];
    #pragma unroll
    for (int u = 0; u < 2; ++u) {
        const short* qbase = qb + (((size_t)(b * 8 + h)) * 2048 + q0 + wave * 32 + u * 16 + l16) * 128;
        #pragma unroll
        for (int ks = 0; ks < 4; ++ks)
            qf[ks][u] = *(const short8*)&qbase[ks * 32 + quad * 8];
    }

    const short*    kbase  = kb + (size_t)(b * 2 + kv) * 2048 * 128;
    const _Float16* vtbase = vt + (size_t)(b * 2 + kv) * 128 * 2048;

    // per-lane staging source offsets (pre-swizzled for linear LDS dest)
    int koff[4], voff[4];
    #pragma unroll
    for (int c = 0; c < 4; ++c) {
        const int sidx = (c * 4 + wave) * 64 + lane;      // 16B block 0..1023
        { const int r = sidx >> 4, p = sidx & 15;         // K: 16 blocks/row
          koff[c] = r * 128 + ((p ^ (r & 7)) << 3); }
        { const int r = sidx >> 3, p = sidx & 7;          // VT: 8 blocks/row
          voff[c] = r * 2048 + ((p ^ (r & 7)) << 3); }
    }

    floatx4 O[8][2] = {};
    float lsum[2] = {0.0f, 0.0f};

    // prologue: stage tile 0 into buffer 0
    #pragma unroll
    for (int c = 0; c < 4; ++c) {
        __builtin_amdgcn_global_load_lds(
            (const __attribute__((address_space(1))) unsigned int*)(kbase + koff[c]),
            (__attribute__((address_space(3))) unsigned int*)&Ks[0][(c * 4 + wave) * 512],
            16, 0, 0);
        __builtin_amdgcn_global_load_lds(
            (const __attribute__((address_space(1))) unsigned int*)(vtbase + voff[c]),
            (__attribute__((address_space(3))) unsigned int*)&VTs[0][(c * 4 + wave) * 512],
            16, 0, 0);
    }

    for (int kt = 0; kt < 32; ++kt) {
        const int cur = kt & 1;
        __syncthreads();   // drains vmcnt (tile kt staged) + prev ds_reads

        if (kt + 1 < 32) {
            const short*    kg = kbase  + (size_t)(kt + 1) * 8192;
            const _Float16* vg = vtbase + (kt + 1) * 64;
            #pragma unroll
            for (int c = 0; c < 4; ++c) {
                __builtin_amdgcn_global_load_lds(
                    (const __attribute__((address_space(1))) unsigned int*)(kg + koff[c]),
                    (__attribute__((address_space(3))) unsigned int*)&Ks[cur ^ 1][(c * 4 + wave) * 512],
                    16, 0, 0);
                __builtin_amdgcn_global_load_lds(
                    (const __attribute__((address_space(1))) unsigned int*)(vg + voff[c]),
                    (__attribute__((address_space(3))) unsigned int*)&VTs[cur ^ 1][(c * 4 + wave) * 512],
                    16, 0, 0);
            }
        }

        #pragma unroll
        for (int t = 0; t < 2; ++t) {
            // ---- S^T = K Q^T for 32 k-rows, both q-subtiles
            floatx4 ST[2][2];
            #pragma unroll
            for (int j = 0; j < 2; ++j) {
                ST[j][0] = (floatx4){0.f, 0.f, 0.f, 0.f};
                ST[j][1] = (floatx4){0.f, 0.f, 0.f, 0.f};
                const int krow = (2 * t + j) * 16 + l16;
                #pragma unroll
                for (int ks = 0; ks < 4; ++ks) {
                    const short8 af = *(const short8*)&Ks[cur][krow * 128 + (((ks * 4 + quad) ^ (l16 & 7)) << 3)];
                    ST[j][0] = __builtin_amdgcn_mfma_f32_16x16x32_bf16(af, qf[ks][0], ST[j][0], 0, 0, 0);
                    ST[j][1] = __builtin_amdgcn_mfma_f32_16x16x32_bf16(af, qf[ks][1], ST[j][1], 0, 0, 0);
                }
            }

            // ---- p = exp2(s*log2e - PSH2) = exp(s - PSHIFT); pack f16
            half8 pf[2];
            #pragma unroll
            for (int u = 0; u < 2; ++u) {
                #pragma unroll
                for (int r = 0; r < 4; ++r) {
                    const float plo = exp2f(fmaf(ST[0][u][r], LOG2E_, -PSH2_));
                    const float phi = exp2f(fmaf(ST[1][u][r], LOG2E_, -PSH2_));
                    lsum[u] += plo + phi;
                    pf[u][r]     = (_Float16)plo;
                    pf[u][4 + r] = (_Float16)phi;
                }
            }

            // ---- O^T += V^T P^T (K=32 f16, A-frag read feeds both u)
            #pragma unroll
            for (int dt = 0; dt < 8; ++dt) {
                const half8 va = *(const half8*)&VTs[cur][(dt * 16 + l16) * 64 + (((4 * t + quad) ^ (l16 & 7)) << 3)];
                O[dt][0] = __builtin_amdgcn_mfma_f32_16x16x32_f16(va, pf[0], O[dt][0], 0, 0, 0);
                O[dt][1] = __builtin_amdgcn_mfma_f32_16x16x32_f16(va, pf[1], O[dt][1], 0, 0, 0);
            }
        }
    }

    // ---- epilogue: reduce lsum across quads; O/l * sigmoid(gate) ----
    #pragma unroll
    for (int u = 0; u < 2; ++u) {
        float ps = lsum[u];
        ps += __shfl_xor(ps, 16);
        ps += __shfl_xor(ps, 32);
        const float invl = 1.0f / ps;
        const int s = q0 + wave * 32 + u * 16 + l16;
        const size_t base = ((size_t)b * 2048 + s) * 1024 + h * 128;
        #pragma unroll
        for (int dt = 0; dt < 8; ++dt) {
            const int d0 = dt * 16 + quad * 4;
            const short4 g4 = *(const short4*)&gateb[base + d0];
            short4 o4;
            o4.x = f2bf(O[dt][u][0] * invl * (1.0f / (1.0f + __expf(-bf2f(g4.x)))));
            o4.y = f2bf(O[dt][u][1] * invl * (1.0f / (1.0f + __expf(-bf2f(g4.y)))));
            o4.z = f2bf(O[dt][u][2] * invl * (1.0f / (1.0f + __expf(-bf2f(g4.z)))));
            o4.w = f2bf(O[dt][u][3] * invl * (1.0f / (1.0f + __expf(-bf2f(g4.w)))));
            *(short4*)&xo[base + d0] = o4;
        }
    }
}

// ---------------------------------------------------------------------------
// Pass 4: output projection, bf16 MFMA + XCD row-panel swizzle.
// ---------------------------------------------------------------------------
__global__ __launch_bounds__(256) void out_mfma(
    const short* __restrict__ Ag, const short* __restrict__ Bg,
    const float* __restrict__ bo, float* __restrict__ Y)
{
    __shared__ short As[128 * 64];
    __shared__ short Bs[128 * 64];
    const int tid = threadIdx.x;
    const int wave = tid >> 6, lane = tid & 63;
    const int quad = lane >> 4, l16 = lane & 15;
    const int wm = wave & 1, wn = wave >> 1;
    const int lin = blockIdx.x;
    const int xcd = lin & 7;
    const int idx = lin >> 3;                  // 0..63
    const int m0 = (xcd * 8 + (idx >> 3)) * 128;
    const int n0 = (idx & 7) * 128;

    floatx4 acc[4][4] = {};

    for (int k0 = 0; k0 < 1024; k0 += 64) {
        __syncthreads();
        #pragma unroll
        for (int c = 0; c < 4; ++c) {
            const int blk = (c * 4 + wave) * 64 + lane;
            const int row = blk >> 3, p = blk & 7;
            const int col = (p ^ (row & 7)) << 3;
            __builtin_amdgcn_global_load_lds(
                (const __attribute__((address_space(1))) unsigned int*)(Ag + (size_t)(m0 + row) * 1024 + k0 + col),
                (__attribute__((address_space(3))) unsigned int*)&As[(c * 4 + wave) * 512],
                16, 0, 0);
            __builtin_amdgcn_global_load_lds(
                (const __attribute__((address_space(1))) unsigned int*)(Bg + (size_t)(n0 + row) * 1024 + k0 + col),
                (__attribute__((address_space(3))) unsigned int*)&Bs[(c * 4 + wave) * 512],
                16, 0, 0);
        }
        __syncthreads();
        #pragma unroll
        for (int ks = 0; ks < 2; ++ks) {
            short8 af[4], bfr[4];
            #pragma unroll
            for (int mt = 0; mt < 4; ++mt) {
                const int row = wm * 64 + mt * 16 + l16;
                const int p = (ks * 4 + quad) ^ (row & 7);
                af[mt] = *(const short8*)&As[row * 64 + p * 8];
            }
            #pragma unroll
            for (int nt = 0; nt < 4; ++nt) {
                const int row = wn * 64 + nt * 16 + l16;
                const int p = (ks * 4 + quad) ^ (row & 7);
                bfr[nt] = *(const short8*)&Bs[row * 64 + p * 8];
            }
            #pragma unroll
            for (int mt = 0; mt < 4; ++mt)
                #pragma unroll
                for (int nt = 0; nt < 4; ++nt)
                    acc[mt][nt] = __builtin_amdgcn_mfma_f32_16x16x32_bf16(af[mt], bfr[nt], acc[mt][nt], 0, 0, 0);
        }
    }

    #pragma unroll
    for (int nt = 0; nt < 4; ++nt) {
        const int n = n0 + wn * 64 + nt * 16 + l16;
        const float bias = bo[n];
        #pragma unroll
        for (int mt = 0; mt < 4; ++mt) {
            #pragma unroll
            for (int r = 0; r < 4; ++r) {
                const int m = m0 + wm * 64 + mt * 16 + quad * 4 + r;
                Y[(size_t)m * 1024 + n] = acc[mt][nt][r] + bias;
            }
        }
    }
}

// ---------------------------------------------------------------------------
extern "C" void kernel_launch(void* const* d_in, const int* in_sizes, int n_in,
                              void* d_out, int out_size, void* d_ws, size_t ws_size,
                              hipStream_t stream) {
    (void)in_sizes; (void)n_in; (void)out_size; (void)ws_size;
    const float* hs   = (const float*)d_in[0];
    const float* rope = (const float*)d_in[1];
    const float* Wq   = (const float*)d_in[2];
    const float* bq   = (const float*)d_in[3];
    const float* Wk   = (const float*)d_in[4];
    const float* bk   = (const float*)d_in[5];
    const float* Wv   = (const float*)d_in[6];
    const float* bv   = (const float*)d_in[7];
    const float* Wo   = (const float*)d_in[8];
    const float* bo   = (const float*)d_in[9];
    const float* qw   = (const float*)d_in[10];
    const float* kw   = (const float*)d_in[11];
    float* out = (float*)d_out;

    // ws layout (2B elems unless noted), total ~66.3 MB:
    short* qb    = (short*)d_ws;                  // 8388608
    short* kbuf  = qb    + (size_t)8388608;       // 2097152
    short* vb    = kbuf  + (size_t)2097152;       // 2097152
    _Float16* vt = (_Float16*)(vb + (size_t)2097152);  // 2097152 f16
    short* gateb = (short*)(vt + (size_t)2097152);     // 8388608
    short* xb    = gateb + (size_t)8388608;       // 8388608 (Xb, then xo)
    short* wt    = xb    + (size_t)8388608;       // 2621440
    short* wot   = wt    + (size_t)2621440;       // 1048576
    float* bcat  = (float*)(wot + (size_t)1048576);  // 2560 fp32

    prep_fused<<<dim3(11776), 256, 0, stream>>>(hs, xb, bq, bk, bv, bcat,
                                                Wq, Wk, Wv, Wo, wt, wot);
    qkv_mfma<<<dim3(1280), 256, 0, stream>>>(xb, wt, bcat, qb, kbuf, vb, gateb);
    norm_vtrans<<<dim3(22528), 256, 0, stream>>>(qb, kbuf, rope, qw, kw, vb, vt);
    attn_mfma<<<dim3(16, 32), 256, 0, stream>>>(qb, kbuf, vt, gateb, xb);
    out_mfma<<<dim3(512), 256, 0, stream>>>(xb, wot, bo, out);
}

// Round 7
// 296.464 us; speedup vs baseline: 1.0460x; 1.0460x over previous
//
#include <hip/hip_runtime.h>
#include <math.h>

// B=4, S=2048, HID=1024, H=8, KV=2, HD=128, G=4, M=8192
#define SCALE_ 0.08838834764831845f  // 1/sqrt(128)
#define PSHIFT 8.0f  // softmax exponent shift: keeps exp(s-PSHIFT) inside f16
                     // range. Shift cancels exactly in O/lsum.

typedef __attribute__((ext_vector_type(8))) short short8;     // 8 bf16 = 4 VGPR
typedef __attribute__((ext_vector_type(4))) float floatx4;
typedef __attribute__((ext_vector_type(4))) _Float16 half4;   // 4 f16 = 2 VGPR
typedef __attribute__((ext_vector_type(8))) _Float16 half8;   // 8 f16 = 4 VGPR

__device__ inline short f2bf(float x) {
    union { float f; unsigned u; } v; v.f = x;
    unsigned r = v.u + 0x7fff + ((v.u >> 16) & 1);   // RNE
    return (short)(r >> 16);
}
__device__ inline float bf2f(short h) {
    union { float f; unsigned u; } v; v.u = ((unsigned)(unsigned short)h) << 16;
    return v.f;
}

// ---------------------------------------------------------------------------
// Prep (fused): blocks [0,8192) = X fp32->bf16 + bias concat;
//               blocks [8192,11776) = weight transpose+convert.
// ---------------------------------------------------------------------------
__global__ __launch_bounds__(256) void prep_fused(
    const float* __restrict__ X, short* __restrict__ Xb,
    const float* __restrict__ bq, const float* __restrict__ bk2,
    const float* __restrict__ bv2, float* __restrict__ bcat,
    const float* __restrict__ Wq, const float* __restrict__ Wk,
    const float* __restrict__ Wv, const float* __restrict__ Wo,
    short* __restrict__ Wt, short* __restrict__ Wot)
{
    __shared__ float T[32][33];
    const int bid = blockIdx.x;
    const int t = threadIdx.x;
    if (bid < 8192) {
        const int gid = bid * 256 + t;
        if (gid < 2097152) {
            const float4 v = ((const float4*)X)[gid];
            short4 o;
            o.x = f2bf(v.x); o.y = f2bf(v.y); o.z = f2bf(v.z); o.w = f2bf(v.w);
            ((short4*)Xb)[gid] = o;
        }
        if (gid < 2560)
            bcat[gid] = (gid < 2048) ? bq[gid]
                      : (gid < 2304) ? bk2[gid - 2048] : bv2[gid - 2304];
        return;
    }
    const int t2 = bid - 8192;
    const int k0 = (t2 & 31) * 32;
    const int ny = t2 >> 5;
    const float* src; int ldn, ncol0, nrow0; short* dst;
    if (ny < 80) {
        const int n0 = ny * 32;
        if (n0 < 2048)      { src = Wq; ldn = 2048; ncol0 = n0; }
        else if (n0 < 2304) { src = Wk; ldn = 256;  ncol0 = n0 - 2048; }
        else                { src = Wv; ldn = 256;  ncol0 = n0 - 2304; }
        dst = Wt; nrow0 = n0;
    } else {
        const int n0 = (ny - 80) * 32;
        src = Wo; ldn = 1024; ncol0 = n0; dst = Wot; nrow0 = n0;
    }
    {
        const int r = t >> 3, c4 = (t & 7) * 4;
        const float4 v = *(const float4*)&src[(size_t)(k0 + r) * ldn + ncol0 + c4];
        T[r][c4 + 0] = v.x; T[r][c4 + 1] = v.y; T[r][c4 + 2] = v.z; T[r][c4 + 3] = v.w;
    }
    __syncthreads();
    {
        const int nr = t >> 3, kc4 = (t & 7) * 4;
        short4 o;
        o.x = f2bf(T[kc4 + 0][nr]);
        o.y = f2bf(T[kc4 + 1][nr]);
        o.z = f2bf(T[kc4 + 2][nr]);
        o.w = f2bf(T[kc4 + 3][nr]);
        *(short4*)&dst[(size_t)(nrow0 + nr) * 1024 + k0 + kc4] = o;
    }
}

// ---------------------------------------------------------------------------
// Pass 1: QKV+gate projection, bf16 MFMA (m97 structure) + XCD row-panel
// swizzle (XCD x owns row-blocks [x*8, x*8+8), sweeping all 20 col-blocks:
// A-panel L2-resident, B streams in column order).
// ---------------------------------------------------------------------------
__global__ __launch_bounds__(256) void qkv_mfma(
    const short* __restrict__ Ag, const short* __restrict__ Bg,
    const float* __restrict__ bcat,
    short* __restrict__ qb, short* __restrict__ kb,
    short* __restrict__ vb, short* __restrict__ gateb)
{
    __shared__ short As[128 * 64];
    __shared__ short Bs[128 * 64];
    const int tid = threadIdx.x;
    const int wave = tid >> 6, lane = tid & 63;
    const int quad = lane >> 4, l16 = lane & 15;
    const int wm = wave & 1, wn = wave >> 1;
    const int lin = blockIdx.x;
    const int xcd = lin & 7;
    const int idx = lin >> 3;                  // 0..159
    const int rr_ = idx / 20;                  // 0..7
    const int m0 = (xcd * 8 + rr_) * 128;
    const int n0 = (idx - rr_ * 20) * 128;

    floatx4 acc[4][4] = {};

    for (int k0 = 0; k0 < 1024; k0 += 64) {
        __syncthreads();
        #pragma unroll
        for (int c = 0; c < 4; ++c) {
            const int blk = (c * 4 + wave) * 64 + lane;   // 16B-block 0..1023
            const int row = blk >> 3, p = blk & 7;
            const int col = (p ^ (row & 7)) << 3;
            __builtin_amdgcn_global_load_lds(
                (const __attribute__((address_space(1))) unsigned int*)(Ag + (size_t)(m0 + row) * 1024 + k0 + col),
                (__attribute__((address_space(3))) unsigned int*)&As[(c * 4 + wave) * 512],
                16, 0, 0);
            __builtin_amdgcn_global_load_lds(
                (const __attribute__((address_space(1))) unsigned int*)(Bg + (size_t)(n0 + row) * 1024 + k0 + col),
                (__attribute__((address_space(3))) unsigned int*)&Bs[(c * 4 + wave) * 512],
                16, 0, 0);
        }
        __syncthreads();
        #pragma unroll
        for (int ks = 0; ks < 2; ++ks) {
            short8 af[4], bfr[4];
            #pragma unroll
            for (int mt = 0; mt < 4; ++mt) {
                const int row = wm * 64 + mt * 16 + l16;
                const int p = (ks * 4 + quad) ^ (row & 7);
                af[mt] = *(const short8*)&As[row * 64 + p * 8];
            }
            #pragma unroll
            for (int nt = 0; nt < 4; ++nt) {
                const int row = wn * 64 + nt * 16 + l16;
                const int p = (ks * 4 + quad) ^ (row & 7);
                bfr[nt] = *(const short8*)&Bs[row * 64 + p * 8];
            }
            #pragma unroll
            for (int mt = 0; mt < 4; ++mt)
                #pragma unroll
                for (int nt = 0; nt < 4; ++nt)
                    acc[mt][nt] = __builtin_amdgcn_mfma_f32_16x16x32_bf16(af[mt], bfr[nt], acc[mt][nt], 0, 0, 0);
        }
    }

    #pragma unroll
    for (int nt = 0; nt < 4; ++nt) {
        const int n = n0 + wn * 64 + nt * 16 + l16;
        const float bias = bcat[n];
        #pragma unroll
        for (int mt = 0; mt < 4; ++mt) {
            #pragma unroll
            for (int r = 0; r < 4; ++r) {
                const int m = m0 + wm * 64 + mt * 16 + quad * 4 + r;
                const int b = m >> 11, s = m & 2047;
                const short o = f2bf(acc[mt][nt][r] + bias);
                if (n < 2048) {
                    const int kv = n >> 10, rr = n & 1023;
                    if (rr < 512) {
                        const int h = kv * 4 + (rr >> 7), d = rr & 127;
                        qb[(((size_t)(b * 8 + h)) * 2048 + s) * 128 + d] = o;
                    } else {
                        const int r2 = rr - 512;
                        const int h = kv * 4 + (r2 >> 7), d = r2 & 127;
                        gateb[(size_t)m * 1024 + h * 128 + d] = o;
                    }
                } else if (n < 2304) {
                    const int c = n - 2048;
                    kb[(((size_t)(b * 2 + (c >> 7))) * 2048 + s) * 128 + (c & 127)] = o;
                } else {
                    const int c = n - 2304;
                    vb[(((size_t)(b * 2 + (c >> 7))) * 2048 + s) * 128 + (c & 127)] = o;
                }
            }
        }
    }
}

// ---------------------------------------------------------------------------
// Pass 2 (fused): blocks [0,20480) = RMSNorm+RoPE on q/k;
//                 blocks [20480,22528) = V transpose with k-permutation.
// ---------------------------------------------------------------------------
__global__ __launch_bounds__(256) void norm_vtrans(
    short* __restrict__ qb, short* __restrict__ kb,
    const float* __restrict__ rope,
    const float* __restrict__ qw, const float* __restrict__ kw,
    const short* __restrict__ vb, _Float16* __restrict__ vt)
{
    __shared__ float T[32][33];
    const int bid = blockIdx.x;
    const int t = threadIdx.x;
    if (bid < 20480) {
        const int row = bid * 4 + (t >> 6);
        short* base; const float* w; int s; float scl;
        if (row < 65536) { base = qb + (size_t)row * 128; s = row & 2047; w = qw; scl = SCALE_; }
        else { const int r2 = row - 65536; base = kb + (size_t)r2 * 128; s = r2 & 2047; w = kw; scl = 1.0f; }
        const int lane = t & 63;
        const short2 xv = *(const short2*)&base[lane * 2];
        const float x0 = bf2f(xv.x), x1 = bf2f(xv.y);
        float ssq = x0 * x0 + x1 * x1;
        #pragma unroll
        for (int off = 1; off < 64; off <<= 1) ssq += __shfl_xor(ssq, off);
        const float inv = rsqrtf(ssq * (1.0f / 128.0f) + 1e-6f);
        const float a = x0 * inv * w[lane * 2];
        const float b = x1 * inv * w[lane * 2 + 1];
        const float* er = rope + (size_t)s * 256;
        const float sin0 = er[lane * 2], sin1 = er[lane * 2 + 1];
        const float cos0 = er[128 + lane * 2], cos1 = er[128 + lane * 2 + 1];
        short2 o;
        o.x = f2bf((a * cos0 - b * sin0) * scl);
        o.y = f2bf((b * cos1 + a * sin1) * scl);
        *(short2*)&base[lane * 2] = o;
        return;
    }
    // ---- V transpose: bf16 (B,KV,S,HD) -> VT (B,KV,HD,S) f16, s-permuted
    // within each 32-block (4q+r -> 8q+r ; 16+4q+r -> 8q+4+r) to match the
    // K=32 f16 MFMA B-frag slots of the QK^T C-layout.
    const int t2 = bid - 20480;
    const int s0 = (t2 & 63) * 32, d0 = ((t2 >> 6) & 3) * 32, bk = t2 >> 8;
    const short* src = vb + ((size_t)bk * 2048 + s0) * 128 + d0;
    {
        const int sr = t >> 3, c4 = (t & 7) * 4;
        const short4 xv = *(const short4*)&src[sr * 128 + c4];
        T[sr][c4 + 0] = bf2f(xv.x);
        T[sr][c4 + 1] = bf2f(xv.y);
        T[sr][c4 + 2] = bf2f(xv.z);
        T[sr][c4 + 3] = bf2f(xv.w);
    }
    __syncthreads();
    {
        const int dr = t >> 3, sc4 = (t & 7) * 4;
        const int cs = sc4 >> 2;                                   // chunk 0..7
        const int nc = (cs < 4) ? (cs << 1) : (((cs - 4) << 1) | 1); // permuted
        half4 o;
        o[0] = (_Float16)T[sc4 + 0][dr];
        o[1] = (_Float16)T[sc4 + 1][dr];
        o[2] = (_Float16)T[sc4 + 2][dr];
        o[3] = (_Float16)T[sc4 + 3][dr];
        *(half4*)&vt[((size_t)bk * 128 + d0 + dr) * 2048 + s0 + nc * 4] = o;
    }
}

// ---------------------------------------------------------------------------
// Pass 3: MFMA flash attention + fused sigmoid gating. Round-15:
// EXACT restore of the round-1 (87.8 us) attn kernel. Ledger re-analysis:
// the regression common to r2-r6 was NOT the XCD swizzle (r6: no swizzle,
// still 102.5) and NOT setprio (r4) -- it was exp2f(): without -ffast-math,
// plain exp2f lowers to OCML's precise path (~8-10 VALU ops + fixup) vs
// __expf's native v_mul+v_exp_f32. Evidence: VGPR 108->124 and absolute
// VALU-busy time +40% across r2-r6 with structure otherwise identical.
// 1024 exp calls/thread x ~7 extra ops ~= the 10-15 us regression.
// Structure: 256 thr, 4 waves x 32 q rows, QBLK=128, dbuf gload_lds,
// one barrier per kt, launch_bounds(256,2), __expf softmax.
// ---------------------------------------------------------------------------
__global__ __launch_bounds__(256, 2) void attn_mfma(
    const short* __restrict__ qb, const short* __restrict__ kb,
    const _Float16* __restrict__ vt, const short* __restrict__ gateb,
    short* __restrict__ xo)
{
    __shared__ short    Ks[2][64 * 128];    // 16 KB per buffer
    __shared__ _Float16 VTs[2][128 * 64];   // 16 KB per buffer

    const int tid = threadIdx.x;
    const int wave = tid >> 6, lane = tid & 63;
    const int quad = lane >> 4, l16 = lane & 15;
    const int bh = blockIdx.y, b = bh >> 3, h = bh & 7, kv = h >> 2;
    const int q0 = blockIdx.x * 128;

    // Q B-frags: qf[ks][u]: B[k=quad*8+j][n=l16] = Q[q0+wave*32+u*16+l16][ks*32+quad*8+j]
    short8 qf[4][2];
    #pragma unroll
    for (int u = 0; u < 2; ++u) {
        const short* qbase = qb + (((size_t)(b * 8 + h)) * 2048 + q0 + wave * 32 + u * 16 + l16) * 128;
        #pragma unroll
        for (int ks = 0; ks < 4; ++ks)
            qf[ks][u] = *(const short8*)&qbase[ks * 32 + quad * 8];
    }

    const short*    kbase  = kb + (size_t)(b * 2 + kv) * 2048 * 128;
    const _Float16* vtbase = vt + (size_t)(b * 2 + kv) * 128 * 2048;

    // per-lane staging source offsets (pre-swizzled for linear LDS dest)
    int koff[4], voff[4];
    #pragma unroll
    for (int c = 0; c < 4; ++c) {
        const int sidx = (c * 4 + wave) * 64 + lane;      // 16B block 0..1023
        { const int r = sidx >> 4, p = sidx & 15;         // K: 16 blocks/row
          koff[c] = r * 128 + ((p ^ (r & 7)) << 3); }
        { const int r = sidx >> 3, p = sidx & 7;          // VT: 8 blocks/row
          voff[c] = r * 2048 + ((p ^ (r & 7)) << 3); }
    }

    floatx4 O[8][2] = {};
    float lsum[2] = {0.0f, 0.0f};

    // prologue: stage tile 0 into buffer 0
    #pragma unroll
    for (int c = 0; c < 4; ++c) {
        __builtin_amdgcn_global_load_lds(
            (const __attribute__((address_space(1))) unsigned int*)(kbase + koff[c]),
            (__attribute__((address_space(3))) unsigned int*)&Ks[0][(c * 4 + wave) * 512],
            16, 0, 0);
        __builtin_amdgcn_global_load_lds(
            (const __attribute__((address_space(1))) unsigned int*)(vtbase + voff[c]),
            (__attribute__((address_space(3))) unsigned int*)&VTs[0][(c * 4 + wave) * 512],
            16, 0, 0);
    }

    for (int kt = 0; kt < 32; ++kt) {
        const int cur = kt & 1;
        __syncthreads();   // drains vmcnt (tile kt staged) + prev ds_reads

        if (kt + 1 < 32) {
            const short*    kg = kbase  + (size_t)(kt + 1) * 8192;
            const _Float16* vg = vtbase + (kt + 1) * 64;
            #pragma unroll
            for (int c = 0; c < 4; ++c) {
                __builtin_amdgcn_global_load_lds(
                    (const __attribute__((address_space(1))) unsigned int*)(kg + koff[c]),
                    (__attribute__((address_space(3))) unsigned int*)&Ks[cur ^ 1][(c * 4 + wave) * 512],
                    16, 0, 0);
                __builtin_amdgcn_global_load_lds(
                    (const __attribute__((address_space(1))) unsigned int*)(vg + voff[c]),
                    (__attribute__((address_space(3))) unsigned int*)&VTs[cur ^ 1][(c * 4 + wave) * 512],
                    16, 0, 0);
            }
        }

        #pragma unroll
        for (int t = 0; t < 2; ++t) {
            // ---- S^T = K Q^T for 32 k-rows, both q-subtiles
            floatx4 ST[2][2];
            #pragma unroll
            for (int j = 0; j < 2; ++j) {
                ST[j][0] = (floatx4){0.f, 0.f, 0.f, 0.f};
                ST[j][1] = (floatx4){0.f, 0.f, 0.f, 0.f};
                const int krow = (2 * t + j) * 16 + l16;
                #pragma unroll
                for (int ks = 0; ks < 4; ++ks) {
                    const short8 af = *(const short8*)&Ks[cur][krow * 128 + (((ks * 4 + quad) ^ (l16 & 7)) << 3)];
                    ST[j][0] = __builtin_amdgcn_mfma_f32_16x16x32_bf16(af, qf[ks][0], ST[j][0], 0, 0, 0);
                    ST[j][1] = __builtin_amdgcn_mfma_f32_16x16x32_bf16(af, qf[ks][1], ST[j][1], 0, 0, 0);
                }
            }

            // ---- p = exp(s - PSHIFT); pack f16 (native __expf: mul+exp)
            half8 pf[2];
            #pragma unroll
            for (int u = 0; u < 2; ++u) {
                #pragma unroll
                for (int r = 0; r < 4; ++r) {
                    const float plo = __expf(ST[0][u][r] - PSHIFT);
                    const float phi = __expf(ST[1][u][r] - PSHIFT);
                    lsum[u] += plo + phi;
                    pf[u][r]     = (_Float16)plo;
                    pf[u][4 + r] = (_Float16)phi;
                }
            }

            // ---- O^T += V^T P^T (K=32 f16, A-frag read feeds both u)
            #pragma unroll
            for (int dt = 0; dt < 8; ++dt) {
                const half8 va = *(const half8*)&VTs[cur][(dt * 16 + l16) * 64 + (((4 * t + quad) ^ (l16 & 7)) << 3)];
                O[dt][0] = __builtin_amdgcn_mfma_f32_16x16x32_f16(va, pf[0], O[dt][0], 0, 0, 0);
                O[dt][1] = __builtin_amdgcn_mfma_f32_16x16x32_f16(va, pf[1], O[dt][1], 0, 0, 0);
            }
        }
    }

    // ---- epilogue: reduce lsum across quads; O/l * sigmoid(gate) ----
    #pragma unroll
    for (int u = 0; u < 2; ++u) {
        float ps = lsum[u];
        ps += __shfl_xor(ps, 16);
        ps += __shfl_xor(ps, 32);
        const float invl = 1.0f / ps;
        const int s = q0 + wave * 32 + u * 16 + l16;
        const size_t base = ((size_t)b * 2048 + s) * 1024 + h * 128;
        #pragma unroll
        for (int dt = 0; dt < 8; ++dt) {
            const int d0 = dt * 16 + quad * 4;
            const short4 g4 = *(const short4*)&gateb[base + d0];
            short4 o4;
            o4.x = f2bf(O[dt][u][0] * invl * (1.0f / (1.0f + __expf(-bf2f(g4.x)))));
            o4.y = f2bf(O[dt][u][1] * invl * (1.0f / (1.0f + __expf(-bf2f(g4.y)))));
            o4.z = f2bf(O[dt][u][2] * invl * (1.0f / (1.0f + __expf(-bf2f(g4.z)))));
            o4.w = f2bf(O[dt][u][3] * invl * (1.0f / (1.0f + __expf(-bf2f(g4.w)))));
            *(short4*)&xo[base + d0] = o4;
        }
    }
}

// ---------------------------------------------------------------------------
// Pass 4: output projection, bf16 MFMA + XCD row-panel swizzle.
// ---------------------------------------------------------------------------
__global__ __launch_bounds__(256) void out_mfma(
    const short* __restrict__ Ag, const short* __restrict__ Bg,
    const float* __restrict__ bo, float* __restrict__ Y)
{
    __shared__ short As[128 * 64];
    __shared__ short Bs[128 * 64];
    const int tid = threadIdx.x;
    const int wave = tid >> 6, lane = tid & 63;
    const int quad = lane >> 4, l16 = lane & 15;
    const int wm = wave & 1, wn = wave >> 1;
    const int lin = blockIdx.x;
    const int xcd = lin & 7;
    const int idx = lin >> 3;                  // 0..63
    const int m0 = (xcd * 8 + (idx >> 3)) * 128;
    const int n0 = (idx & 7) * 128;

    floatx4 acc[4][4] = {};

    for (int k0 = 0; k0 < 1024; k0 += 64) {
        __syncthreads();
        #pragma unroll
        for (int c = 0; c < 4; ++c) {
            const int blk = (c * 4 + wave) * 64 + lane;
            const int row = blk >> 3, p = blk & 7;
            const int col = (p ^ (row & 7)) << 3;
            __builtin_amdgcn_global_load_lds(
                (const __attribute__((address_space(1))) unsigned int*)(Ag + (size_t)(m0 + row) * 1024 + k0 + col),
                (__attribute__((address_space(3))) unsigned int*)&As[(c * 4 + wave) * 512],
                16, 0, 0);
            __builtin_amdgcn_global_load_lds(
                (const __attribute__((address_space(1))) unsigned int*)(Bg + (size_t)(n0 + row) * 1024 + k0 + col),
                (__attribute__((address_space(3))) unsigned int*)&Bs[(c * 4 + wave) * 512],
                16, 0, 0);
        }
        __syncthreads();
        #pragma unroll
        for (int ks = 0; ks < 2; ++ks) {
            short8 af[4], bfr[4];
            #pragma unroll
            for (int mt = 0; mt < 4; ++mt) {
                const int row = wm * 64 + mt * 16 + l16;
                const int p = (ks * 4 + quad) ^ (row & 7);
                af[mt] = *(const short8*)&As[row * 64 + p * 8];
            }
            #pragma unroll
            for (int nt = 0; nt < 4; ++nt) {
                const int row = wn * 64 + nt * 16 + l16;
                const int p = (ks * 4 + quad) ^ (row & 7);
                bfr[nt] = *(const short8*)&Bs[row * 64 + p * 8];
            }
            #pragma unroll
            for (int mt = 0; mt < 4; ++mt)
                #pragma unroll
                for (int nt = 0; nt < 4; ++nt)
                    acc[mt][nt] = __builtin_amdgcn_mfma_f32_16x16x32_bf16(af[mt], bfr[nt], acc[mt][nt], 0, 0, 0);
        }
    }

    #pragma unroll
    for (int nt = 0; nt < 4; ++nt) {
        const int n = n0 + wn * 64 + nt * 16 + l16;
        const float bias = bo[n];
        #pragma unroll
        for (int mt = 0; mt < 4; ++mt) {
            #pragma unroll
            for (int r = 0; r < 4; ++r) {
                const int m = m0 + wm * 64 + mt * 16 + quad * 4 + r;
                Y[(size_t)m * 1024 + n] = acc[mt][nt][r] + bias;
            }
        }
    }
}

// ---------------------------------------------------------------------------
extern "C" void kernel_launch(void* const* d_in, const int* in_sizes, int n_in,
                              void* d_out, int out_size, void* d_ws, size_t ws_size,
                              hipStream_t stream) {
    (void)in_sizes; (void)n_in; (void)out_size; (void)ws_size;
    const float* hs   = (const float*)d_in[0];
    const float* rope = (const float*)d_in[1];
    const float* Wq   = (const float*)d_in[2];
    const float* bq   = (const float*)d_in[3];
    const float* Wk   = (const float*)d_in[4];
    const float* bk   = (const float*)d_in[5];
    const float* Wv   = (const float*)d_in[6];
    const float* bv   = (const float*)d_in[7];
    const float* Wo   = (const float*)d_in[8];
    const float* bo   = (const float*)d_in[9];
    const float* qw   = (const float*)d_in[10];
    const float* kw   = (const float*)d_in[11];
    float* out = (float*)d_out;

    // ws layout (2B elems unless noted), total ~66.3 MB:
    short* qb    = (short*)d_ws;                  // 8388608
    short* kbuf  = qb    + (size_t)8388608;       // 2097152
    short* vb    = kbuf  + (size_t)2097152;       // 2097152
    _Float16* vt = (_Float16*)(vb + (size_t)2097152);  // 2097152 f16
    short* gateb = (short*)(vt + (size_t)2097152);     // 8388608
    short* xb    = gateb + (size_t)8388608;       // 8388608 (Xb, then xo)
    short* wt    = xb    + (size_t)8388608;       // 2621440
    short* wot   = wt    + (size_t)2621440;       // 1048576
    float* bcat  = (float*)(wot + (size_t)1048576);  // 2560 fp32

    prep_fused<<<dim3(11776), 256, 0, stream>>>(hs, xb, bq, bk, bv, bcat,
                                                Wq, Wk, Wv, Wo, wt, wot);
    qkv_mfma<<<dim3(1280), 256, 0, stream>>>(xb, wt, bcat, qb, kbuf, vb, gateb);
    norm_vtrans<<<dim3(22528), 256, 0, stream>>>(qb, kbuf, rope, qw, kw, vb, vt);
    attn_mfma<<<dim3(16, 32), 256, 0, stream>>>(qb, kbuf, vt, gateb, xb);
    out_mfma<<<dim3(512), 256, 0, stream>>>(xb, wot, bo, out);
}

// Round 8
// 280.504 us; speedup vs baseline: 1.1055x; 1.0569x over previous
//
#include <hip/hip_runtime.h>
#include <math.h>

// B=4, S=2048, HID=1024, H=8, KV=2, HD=128, G=4, M=8192
#define SCALE_ 0.08838834764831845f  // 1/sqrt(128)
#define PSHIFT 8.0f  // softmax exponent shift: keeps exp(s-PSHIFT) inside f16
                     // range. Shift cancels exactly in O/lsum.

typedef __attribute__((ext_vector_type(8))) short short8;     // 8 bf16 = 4 VGPR
typedef __attribute__((ext_vector_type(4))) float floatx4;
typedef __attribute__((ext_vector_type(4))) _Float16 half4;   // 4 f16 = 2 VGPR
typedef __attribute__((ext_vector_type(8))) _Float16 half8;   // 8 f16 = 4 VGPR

__device__ inline short f2bf(float x) {
    union { float f; unsigned u; } v; v.f = x;
    unsigned r = v.u + 0x7fff + ((v.u >> 16) & 1);   // RNE
    return (short)(r >> 16);
}
__device__ inline float bf2f(short h) {
    union { float f; unsigned u; } v; v.u = ((unsigned)(unsigned short)h) << 16;
    return v.f;
}

// ---------------------------------------------------------------------------
// Prep (fused): blocks [0,8192) = X fp32->bf16 + bias concat;
//               blocks [8192,11776) = weight transpose+convert.
// ---------------------------------------------------------------------------
__global__ __launch_bounds__(256) void prep_fused(
    const float* __restrict__ X, short* __restrict__ Xb,
    const float* __restrict__ bq, const float* __restrict__ bk2,
    const float* __restrict__ bv2, float* __restrict__ bcat,
    const float* __restrict__ Wq, const float* __restrict__ Wk,
    const float* __restrict__ Wv, const float* __restrict__ Wo,
    short* __restrict__ Wt, short* __restrict__ Wot)
{
    __shared__ float T[32][33];
    const int bid = blockIdx.x;
    const int t = threadIdx.x;
    if (bid < 8192) {
        const int gid = bid * 256 + t;
        if (gid < 2097152) {
            const float4 v = ((const float4*)X)[gid];
            short4 o;
            o.x = f2bf(v.x); o.y = f2bf(v.y); o.z = f2bf(v.z); o.w = f2bf(v.w);
            ((short4*)Xb)[gid] = o;
        }
        if (gid < 2560)
            bcat[gid] = (gid < 2048) ? bq[gid]
                      : (gid < 2304) ? bk2[gid - 2048] : bv2[gid - 2304];
        return;
    }
    const int t2 = bid - 8192;
    const int k0 = (t2 & 31) * 32;
    const int ny = t2 >> 5;
    const float* src; int ldn, ncol0, nrow0; short* dst;
    if (ny < 80) {
        const int n0 = ny * 32;
        if (n0 < 2048)      { src = Wq; ldn = 2048; ncol0 = n0; }
        else if (n0 < 2304) { src = Wk; ldn = 256;  ncol0 = n0 - 2048; }
        else                { src = Wv; ldn = 256;  ncol0 = n0 - 2304; }
        dst = Wt; nrow0 = n0;
    } else {
        const int n0 = (ny - 80) * 32;
        src = Wo; ldn = 1024; ncol0 = n0; dst = Wot; nrow0 = n0;
    }
    {
        const int r = t >> 3, c4 = (t & 7) * 4;
        const float4 v = *(const float4*)&src[(size_t)(k0 + r) * ldn + ncol0 + c4];
        T[r][c4 + 0] = v.x; T[r][c4 + 1] = v.y; T[r][c4 + 2] = v.z; T[r][c4 + 3] = v.w;
    }
    __syncthreads();
    {
        const int nr = t >> 3, kc4 = (t & 7) * 4;
        short4 o;
        o.x = f2bf(T[kc4 + 0][nr]);
        o.y = f2bf(T[kc4 + 1][nr]);
        o.z = f2bf(T[kc4 + 2][nr]);
        o.w = f2bf(T[kc4 + 3][nr]);
        *(short4*)&dst[(size_t)(nrow0 + nr) * 1024 + k0 + kc4] = o;
    }
}

// ---------------------------------------------------------------------------
// Pass 1: QKV+gate projection, bf16 MFMA (m97 structure) + XCD row-panel
// swizzle. Round-16: FUSED EPILOGUE — every 128-col n-block aligns with one
// head's full d=128 range, so the block holds complete rows:
//   Q/K blocks: RMSNorm on f32 acc (shfl over l16 + LDS across wn waves) +
//               RoPE (pair element d^1 is the neighboring lane -> shfl_xor 1)
//               + scale, stored bf16. One less bf16 quantization than the
//               old separate pass.
//   V blocks:   f16 convert + LDS transpose ([128][68] scratch) + direct
//               permuted write to vt (vb eliminated).
//   Gate:       plain store (unchanged).
// norm_vtrans kernel deleted.
// ---------------------------------------------------------------------------
__global__ __launch_bounds__(256) void qkv_mfma(
    const short* __restrict__ Ag, const short* __restrict__ Bg,
    const float* __restrict__ bcat,
    const float* __restrict__ rope,
    const float* __restrict__ qw, const float* __restrict__ kw,
    short* __restrict__ qb, short* __restrict__ kb,
    _Float16* __restrict__ vt, short* __restrict__ gateb)
{
    __shared__ short As[128 * 64];
    __shared__ short Bs[128 * 64];
    __shared__ _Float16 vscr[128 * 68];   // V-transpose scratch (17 KB)
    __shared__ float sred[256];           // rmsnorm cross-wave scratch
    const int tid = threadIdx.x;
    const int wave = tid >> 6, lane = tid & 63;
    const int quad = lane >> 4, l16 = lane & 15;
    const int wm = wave & 1, wn = wave >> 1;
    const int lin = blockIdx.x;
    const int xcd = lin & 7;
    const int idx = lin >> 3;                  // 0..159
    const int rr_ = idx / 20;                  // 0..7
    const int m0 = (xcd * 8 + rr_) * 128;
    const int n0 = (idx - rr_ * 20) * 128;

    floatx4 acc[4][4] = {};

    for (int k0 = 0; k0 < 1024; k0 += 64) {
        __syncthreads();
        #pragma unroll
        for (int c = 0; c < 4; ++c) {
            const int blk = (c * 4 + wave) * 64 + lane;   // 16B-block 0..1023
            const int row = blk >> 3, p = blk & 7;
            const int col = (p ^ (row & 7)) << 3;
            __builtin_amdgcn_global_load_lds(
                (const __attribute__((address_space(1))) unsigned int*)(Ag + (size_t)(m0 + row) * 1024 + k0 + col),
                (__attribute__((address_space(3))) unsigned int*)&As[(c * 4 + wave) * 512],
                16, 0, 0);
            __builtin_amdgcn_global_load_lds(
                (const __attribute__((address_space(1))) unsigned int*)(Bg + (size_t)(n0 + row) * 1024 + k0 + col),
                (__attribute__((address_space(3))) unsigned int*)&Bs[(c * 4 + wave) * 512],
                16, 0, 0);
        }
        __syncthreads();
        #pragma unroll
        for (int ks = 0; ks < 2; ++ks) {
            short8 af[4], bfr[4];
            #pragma unroll
            for (int mt = 0; mt < 4; ++mt) {
                const int row = wm * 64 + mt * 16 + l16;
                const int p = (ks * 4 + quad) ^ (row & 7);
                af[mt] = *(const short8*)&As[row * 64 + p * 8];
            }
            #pragma unroll
            for (int nt = 0; nt < 4; ++nt) {
                const int row = wn * 64 + nt * 16 + l16;
                const int p = (ks * 4 + quad) ^ (row & 7);
                bfr[nt] = *(const short8*)&Bs[row * 64 + p * 8];
            }
            #pragma unroll
            for (int mt = 0; mt < 4; ++mt)
                #pragma unroll
                for (int nt = 0; nt < 4; ++nt)
                    acc[mt][nt] = __builtin_amdgcn_mfma_f32_16x16x32_bf16(af[mt], bfr[nt], acc[mt][nt], 0, 0, 0);
        }
    }

    // ---------------- fused epilogue ----------------
    const int dl0 = wn * 64 + l16;             // d for nt: dl0 + nt*16
    float bias4[4];
    #pragma unroll
    for (int nt = 0; nt < 4; ++nt) bias4[nt] = bcat[n0 + dl0 + nt * 16];
    const int nlow = n0 & 1023;

    if (n0 >= 2304) {
        // ================= V: transpose+permute -> vt (f16) =================
        const int kvv = (n0 - 2304) >> 7;
        const int bV = m0 >> 11, s0g = m0 & 2047;
        const size_t vtb = ((size_t)(bV * 2 + kvv)) * 128 * 2048;
        __syncthreads();
        #pragma unroll
        for (int half = 0; half < 2; ++half) {
            if (wn == half) {
                #pragma unroll
                for (int mt = 0; mt < 4; ++mt)
                    #pragma unroll
                    for (int r = 0; r < 4; ++r) {
                        const int sl = wm * 64 + mt * 16 + quad * 4 + r;
                        #pragma unroll
                        for (int nt = 0; nt < 4; ++nt)
                            vscr[sl * 68 + nt * 16 + l16] =
                                (_Float16)(acc[mt][nt][r] + bias4[nt]);
                    }
            }
            __syncthreads();
            {
                const int dl = tid & 63, sch = tid >> 6;
                #pragma unroll
                for (int g = 0; g < 8; ++g) {
                    half4 o;
                    #pragma unroll
                    for (int e = 0; e < 4; ++e)
                        o[e] = vscr[(sch * 32 + g * 4 + e) * 68 + dl];
                    const int ncs = (g < 4) ? (g << 1) : (((g - 4) << 1) | 1);
                    *(half4*)&vt[vtb + (size_t)(half * 64 + dl) * 2048 + s0g + sch * 32 + ncs * 4] = o;
                }
            }
            __syncthreads();
        }
    } else if (n0 < 2048 && nlow >= 512) {
        // ================= gate: plain store =================
        const int h = ((n0 >> 10) << 2) + ((nlow - 512) >> 7);
        #pragma unroll
        for (int nt = 0; nt < 4; ++nt) {
            const int d = dl0 + nt * 16;
            #pragma unroll
            for (int mt = 0; mt < 4; ++mt)
                #pragma unroll
                for (int r = 0; r < 4; ++r) {
                    const int m = m0 + wm * 64 + mt * 16 + quad * 4 + r;
                    gateb[(size_t)m * 1024 + h * 128 + d] = f2bf(acc[mt][nt][r] + bias4[nt]);
                }
        }
    } else {
        // ================= Q or K: RMSNorm + RoPE =================
        const int isQ = (n0 < 2048);
        const int hq  = isQ ? (((n0 >> 10) << 2) + (nlow >> 7)) : 0;
        const int kvk = isQ ? 0 : ((n0 - 2048) >> 7);
        const float* wv = isQ ? qw : kw;
        const float scl = isQ ? SCALE_ : 1.0f;
        short* dst = isQ ? qb : kb;

        __syncthreads();
        float part[4][4];
        #pragma unroll
        for (int mt = 0; mt < 4; ++mt)
            #pragma unroll
            for (int r = 0; r < 4; ++r) {
                float p = 0.f;
                #pragma unroll
                for (int nt = 0; nt < 4; ++nt) {
                    const float x = acc[mt][nt][r] + bias4[nt];
                    p += x * x;
                }
                #pragma unroll
                for (int off = 1; off < 16; off <<= 1)
                    p += __shfl_xor(p, off);
                part[mt][r] = p;
            }
        if (wn == 1 && l16 == 0) {
            #pragma unroll
            for (int mt = 0; mt < 4; ++mt)
                #pragma unroll
                for (int r = 0; r < 4; ++r)
                    sred[wm * 64 + mt * 16 + quad * 4 + r] = part[mt][r];
        }
        __syncthreads();
        if (wn == 0 && l16 == 0) {
            #pragma unroll
            for (int mt = 0; mt < 4; ++mt)
                #pragma unroll
                for (int r = 0; r < 4; ++r) {
                    const int ml = wm * 64 + mt * 16 + quad * 4 + r;
                    const float tot = part[mt][r] + sred[ml];
                    sred[128 + ml] = rsqrtf(tot * (1.0f / 128.0f) + 1e-6f);
                }
        }
        __syncthreads();
        float w4[4];
        #pragma unroll
        for (int nt = 0; nt < 4; ++nt) w4[nt] = wv[dl0 + nt * 16];
        #pragma unroll
        for (int mt = 0; mt < 4; ++mt)
            #pragma unroll
            for (int r = 0; r < 4; ++r) {
                const int m = m0 + wm * 64 + mt * 16 + quad * 4 + r;
                const int bb = m >> 11, s = m & 2047;
                const float inv = sred[128 + wm * 64 + mt * 16 + quad * 4 + r];
                const float* er = rope + (size_t)s * 256;
                const size_t rb = ((size_t)(isQ ? (bb * 8 + hq) : (bb * 2 + kvk)) * 2048 + s) * 128;
                #pragma unroll
                for (int nt = 0; nt < 4; ++nt) {
                    const int d = dl0 + nt * 16;
                    const float xn = (acc[mt][nt][r] + bias4[nt]) * inv * w4[nt];
                    const float pn = __shfl_xor(xn, 1);
                    const float sn = er[d], cn = er[128 + d];
                    const float out = (l16 & 1) ? fmaf(xn, cn, pn * sn)
                                                : fmaf(xn, cn, -pn * sn);
                    dst[rb + d] = f2bf(out * scl);
                }
            }
    }
}

// ---------------------------------------------------------------------------
// Pass 3: MFMA flash attention + fused sigmoid gating — byte-identical to
// round-7/round-1 (87 us): 256 thr, 4 waves x 32 q rows, QBLK=128, dbuf
// gload_lds, one barrier per kt, launch_bounds(256,2), __expf softmax.
// (r2-r6 ledger: exp2f-OCML was the regression; swizzle/setprio/stagger null.)
// ---------------------------------------------------------------------------
__global__ __launch_bounds__(256, 2) void attn_mfma(
    const short* __restrict__ qb, const short* __restrict__ kb,
    const _Float16* __restrict__ vt, const short* __restrict__ gateb,
    short* __restrict__ xo)
{
    __shared__ short    Ks[2][64 * 128];    // 16 KB per buffer
    __shared__ _Float16 VTs[2][128 * 64];   // 16 KB per buffer

    const int tid = threadIdx.x;
    const int wave = tid >> 6, lane = tid & 63;
    const int quad = lane >> 4, l16 = lane & 15;
    const int bh = blockIdx.y, b = bh >> 3, h = bh & 7, kv = h >> 2;
    const int q0 = blockIdx.x * 128;

    // Q B-frags: qf[ks][u]: B[k=quad*8+j][n=l16] = Q[q0+wave*32+u*16+l16][ks*32+quad*8+j]
    short8 qf[4][2];
    #pragma unroll
    for (int u = 0; u < 2; ++u) {
        const short* qbase = qb + (((size_t)(b * 8 + h)) * 2048 + q0 + wave * 32 + u * 16 + l16) * 128;
        #pragma unroll
        for (int ks = 0; ks < 4; ++ks)
            qf[ks][u] = *(const short8*)&qbase[ks * 32 + quad * 8];
    }

    const short*    kbase  = kb + (size_t)(b * 2 + kv) * 2048 * 128;
    const _Float16* vtbase = vt + (size_t)(b * 2 + kv) * 128 * 2048;

    // per-lane staging source offsets (pre-swizzled for linear LDS dest)
    int koff[4], voff[4];
    #pragma unroll
    for (int c = 0; c < 4; ++c) {
        const int sidx = (c * 4 + wave) * 64 + lane;      // 16B block 0..1023
        { const int r = sidx >> 4, p = sidx & 15;         // K: 16 blocks/row
          koff[c] = r * 128 + ((p ^ (r & 7)) << 3); }
        { const int r = sidx >> 3, p = sidx & 7;          // VT: 8 blocks/row
          voff[c] = r * 2048 + ((p ^ (r & 7)) << 3); }
    }

    floatx4 O[8][2] = {};
    float lsum[2] = {0.0f, 0.0f};

    // prologue: stage tile 0 into buffer 0
    #pragma unroll
    for (int c = 0; c < 4; ++c) {
        __builtin_amdgcn_global_load_lds(
            (const __attribute__((address_space(1))) unsigned int*)(kbase + koff[c]),
            (__attribute__((address_space(3))) unsigned int*)&Ks[0][(c * 4 + wave) * 512],
            16, 0, 0);
        __builtin_amdgcn_global_load_lds(
            (const __attribute__((address_space(1))) unsigned int*)(vtbase + voff[c]),
            (__attribute__((address_space(3))) unsigned int*)&VTs[0][(c * 4 + wave) * 512],
            16, 0, 0);
    }

    for (int kt = 0; kt < 32; ++kt) {
        const int cur = kt & 1;
        __syncthreads();   // drains vmcnt (tile kt staged) + prev ds_reads

        if (kt + 1 < 32) {
            const short*    kg = kbase  + (size_t)(kt + 1) * 8192;
            const _Float16* vg = vtbase + (kt + 1) * 64;
            #pragma unroll
            for (int c = 0; c < 4; ++c) {
                __builtin_amdgcn_global_load_lds(
                    (const __attribute__((address_space(1))) unsigned int*)(kg + koff[c]),
                    (__attribute__((address_space(3))) unsigned int*)&Ks[cur ^ 1][(c * 4 + wave) * 512],
                    16, 0, 0);
                __builtin_amdgcn_global_load_lds(
                    (const __attribute__((address_space(1))) unsigned int*)(vg + voff[c]),
                    (__attribute__((address_space(3))) unsigned int*)&VTs[cur ^ 1][(c * 4 + wave) * 512],
                    16, 0, 0);
            }
        }

        #pragma unroll
        for (int t = 0; t < 2; ++t) {
            // ---- S^T = K Q^T for 32 k-rows, both q-subtiles
            floatx4 ST[2][2];
            #pragma unroll
            for (int j = 0; j < 2; ++j) {
                ST[j][0] = (floatx4){0.f, 0.f, 0.f, 0.f};
                ST[j][1] = (floatx4){0.f, 0.f, 0.f, 0.f};
                const int krow = (2 * t + j) * 16 + l16;
                #pragma unroll
                for (int ks = 0; ks < 4; ++ks) {
                    const short8 af = *(const short8*)&Ks[cur][krow * 128 + (((ks * 4 + quad) ^ (l16 & 7)) << 3)];
                    ST[j][0] = __builtin_amdgcn_mfma_f32_16x16x32_bf16(af, qf[ks][0], ST[j][0], 0, 0, 0);
                    ST[j][1] = __builtin_amdgcn_mfma_f32_16x16x32_bf16(af, qf[ks][1], ST[j][1], 0, 0, 0);
                }
            }

            // ---- p = exp(s - PSHIFT); pack f16 (native __expf: mul+exp)
            half8 pf[2];
            #pragma unroll
            for (int u = 0; u < 2; ++u) {
                #pragma unroll
                for (int r = 0; r < 4; ++r) {
                    const float plo = __expf(ST[0][u][r] - PSHIFT);
                    const float phi = __expf(ST[1][u][r] - PSHIFT);
                    lsum[u] += plo + phi;
                    pf[u][r]     = (_Float16)plo;
                    pf[u][4 + r] = (_Float16)phi;
                }
            }

            // ---- O^T += V^T P^T (K=32 f16, A-frag read feeds both u)
            #pragma unroll
            for (int dt = 0; dt < 8; ++dt) {
                const half8 va = *(const half8*)&VTs[cur][(dt * 16 + l16) * 64 + (((4 * t + quad) ^ (l16 & 7)) << 3)];
                O[dt][0] = __builtin_amdgcn_mfma_f32_16x16x32_f16(va, pf[0], O[dt][0], 0, 0, 0);
                O[dt][1] = __builtin_amdgcn_mfma_f32_16x16x32_f16(va, pf[1], O[dt][1], 0, 0, 0);
            }
        }
    }

    // ---- epilogue: reduce lsum across quads; O/l * sigmoid(gate) ----
    #pragma unroll
    for (int u = 0; u < 2; ++u) {
        float ps = lsum[u];
        ps += __shfl_xor(ps, 16);
        ps += __shfl_xor(ps, 32);
        const float invl = 1.0f / ps;
        const int s = q0 + wave * 32 + u * 16 + l16;
        const size_t base = ((size_t)b * 2048 + s) * 1024 + h * 128;
        #pragma unroll
        for (int dt = 0; dt < 8; ++dt) {
            const int d0 = dt * 16 + quad * 4;
            const short4 g4 = *(const short4*)&gateb[base + d0];
            short4 o4;
            o4.x = f2bf(O[dt][u][0] * invl * (1.0f / (1.0f + __expf(-bf2f(g4.x)))));
            o4.y = f2bf(O[dt][u][1] * invl * (1.0f / (1.0f + __expf(-bf2f(g4.y)))));
            o4.z = f2bf(O[dt][u][2] * invl * (1.0f / (1.0f + __expf(-bf2f(g4.z)))));
            o4.w = f2bf(O[dt][u][3] * invl * (1.0f / (1.0f + __expf(-bf2f(g4.w)))));
            *(short4*)&xo[base + d0] = o4;
        }
    }
}

// ---------------------------------------------------------------------------
// Pass 4: output projection, bf16 MFMA + XCD row-panel swizzle.
// ---------------------------------------------------------------------------
__global__ __launch_bounds__(256) void out_mfma(
    const short* __restrict__ Ag, const short* __restrict__ Bg,
    const float* __restrict__ bo, float* __restrict__ Y)
{
    __shared__ short As[128 * 64];
    __shared__ short Bs[128 * 64];
    const int tid = threadIdx.x;
    const int wave = tid >> 6, lane = tid & 63;
    const int quad = lane >> 4, l16 = lane & 15;
    const int wm = wave & 1, wn = wave >> 1;
    const int lin = blockIdx.x;
    const int xcd = lin & 7;
    const int idx = lin >> 3;                  // 0..63
    const int m0 = (xcd * 8 + (idx >> 3)) * 128;
    const int n0 = (idx & 7) * 128;

    floatx4 acc[4][4] = {};

    for (int k0 = 0; k0 < 1024; k0 += 64) {
        __syncthreads();
        #pragma unroll
        for (int c = 0; c < 4; ++c) {
            const int blk = (c * 4 + wave) * 64 + lane;
            const int row = blk >> 3, p = blk & 7;
            const int col = (p ^ (row & 7)) << 3;
            __builtin_amdgcn_global_load_lds(
                (const __attribute__((address_space(1))) unsigned int*)(Ag + (size_t)(m0 + row) * 1024 + k0 + col),
                (__attribute__((address_space(3))) unsigned int*)&As[(c * 4 + wave) * 512],
                16, 0, 0);
            __builtin_amdgcn_global_load_lds(
                (const __attribute__((address_space(1))) unsigned int*)(Bg + (size_t)(n0 + row) * 1024 + k0 + col),
                (__attribute__((address_space(3))) unsigned int*)&Bs[(c * 4 + wave) * 512],
                16, 0, 0);
        }
        __syncthreads();
        #pragma unroll
        for (int ks = 0; ks < 2; ++ks) {
            short8 af[4], bfr[4];
            #pragma unroll
            for (int mt = 0; mt < 4; ++mt) {
                const int row = wm * 64 + mt * 16 + l16;
                const int p = (ks * 4 + quad) ^ (row & 7);
                af[mt] = *(const short8*)&As[row * 64 + p * 8];
            }
            #pragma unroll
            for (int nt = 0; nt < 4; ++nt) {
                const int row = wn * 64 + nt * 16 + l16;
                const int p = (ks * 4 + quad) ^ (row & 7);
                bfr[nt] = *(const short8*)&Bs[row * 64 + p * 8];
            }
            #pragma unroll
            for (int mt = 0; mt < 4; ++mt)
                #pragma unroll
                for (int nt = 0; nt < 4; ++nt)
                    acc[mt][nt] = __builtin_amdgcn_mfma_f32_16x16x32_bf16(af[mt], bfr[nt], acc[mt][nt], 0, 0, 0);
        }
    }

    #pragma unroll
    for (int nt = 0; nt < 4; ++nt) {
        const int n = n0 + wn * 64 + nt * 16 + l16;
        const float bias = bo[n];
        #pragma unroll
        for (int mt = 0; mt < 4; ++mt) {
            #pragma unroll
            for (int r = 0; r < 4; ++r) {
                const int m = m0 + wm * 64 + mt * 16 + quad * 4 + r;
                Y[(size_t)m * 1024 + n] = acc[mt][nt][r] + bias;
            }
        }
    }
}

// ---------------------------------------------------------------------------
extern "C" void kernel_launch(void* const* d_in, const int* in_sizes, int n_in,
                              void* d_out, int out_size, void* d_ws, size_t ws_size,
                              hipStream_t stream) {
    (void)in_sizes; (void)n_in; (void)out_size; (void)ws_size;
    const float* hs   = (const float*)d_in[0];
    const float* rope = (const float*)d_in[1];
    const float* Wq   = (const float*)d_in[2];
    const float* bq   = (const float*)d_in[3];
    const float* Wk   = (const float*)d_in[4];
    const float* bk   = (const float*)d_in[5];
    const float* Wv   = (const float*)d_in[6];
    const float* bv   = (const float*)d_in[7];
    const float* Wo   = (const float*)d_in[8];
    const float* bo   = (const float*)d_in[9];
    const float* qw   = (const float*)d_in[10];
    const float* kw   = (const float*)d_in[11];
    float* out = (float*)d_out;

    // ws layout (2B elems unless noted), total ~66.3 MB:
    short* qb    = (short*)d_ws;                  // 8388608
    short* kbuf  = qb    + (size_t)8388608;       // 2097152
    short* vb    = kbuf  + (size_t)2097152;       // 2097152 (unused now)
    _Float16* vt = (_Float16*)(vb + (size_t)2097152);  // 2097152 f16
    short* gateb = (short*)(vt + (size_t)2097152);     // 8388608
    short* xb    = gateb + (size_t)8388608;       // 8388608 (Xb, then xo)
    short* wt    = xb    + (size_t)8388608;       // 2621440
    short* wot   = wt    + (size_t)2621440;       // 1048576
    float* bcat  = (float*)(wot + (size_t)1048576);  // 2560 fp32

    prep_fused<<<dim3(11776), 256, 0, stream>>>(hs, xb, bq, bk, bv, bcat,
                                                Wq, Wk, Wv, Wo, wt, wot);
    qkv_mfma<<<dim3(1280), 256, 0, stream>>>(xb, wt, bcat, rope, qw, kw,
                                             qb, kbuf, vt, gateb);
    attn_mfma<<<dim3(16, 32), 256, 0, stream>>>(qb, kbuf, vt, gateb, xb);
    out_mfma<<<dim3(512), 256, 0, stream>>>(xb, wot, bo, out);
}